// Round 2
// baseline (112.685 us; speedup 1.0000x reference)
//
#include <hip/hip_runtime.h>
#include <cstdint>
#include <cstddef>

// Problem constants
#define NB 2
#define NF 8
#define NS 4
#define NK 90      // real K (dirs per shell)
#define NP 642     // grid vertices (M)
#define NXYZ 1728  // 12*12*12 (N)
#define KP 96      // K padded to multiple of 32
#define MT 64      // p-tile
#define NT 96      // xyz-tile (1728 = 18*96 exact)
#define PTILES 11  // ceil(642/64)  — looped INSIDE the block
#define NTILES 18
#define ROWB (KP * 2)  // LDS row stride in bytes (96 bf16)

typedef __attribute__((ext_vector_type(8))) __bf16 bf16x8;
typedef __attribute__((ext_vector_type(4))) float f32x4;
typedef __attribute__((ext_vector_type(4))) uint32_t u32x4;

// RNE pack of two f32 -> u32 holding 2 bf16
__device__ __forceinline__ uint32_t pack2bf(float a, float b) {
    uint32_t ua = __builtin_bit_cast(uint32_t, a);
    uint32_t ub = __builtin_bit_cast(uint32_t, b);
    ua += 0x7FFFu + ((ua >> 16) & 1u);
    ub += 0x7FFFu + ((ub >> 16) & 1u);
    return (ua >> 16) | (ub & 0xFFFF0000u);
}

__global__ __launch_bounds__(192, 4) void interp_mfma(
    const float* __restrict__ x, const float* __restrict__ Wm,
    float* __restrict__ y)
{
    // XOR-swizzled LDS tiles: byte-offset ^= ((row&7)<<4). Same formula on
    // write and read sides (validated in round 1: absmax = bf16 rounding).
    __shared__ __align__(16) char As[MT * ROWB];  // 12 KB  A = W[s]^T  [p][k]
    __shared__ __align__(16) char Bs[NT * ROWB];  // 18 KB  B^T        [xyz][k]

    int blk = (int)blockIdx.x;
    const int nt = blk % NTILES; blk /= NTILES;
    const int f  = blk % NF;     blk /= NF;
    const int s  = blk % NS;     blk /= NS;
    const int b  = blk;

    const int tid = (int)threadIdx.x;
    const int n0 = nt * NT;

    // ---- Stage B ONCE: Bs[c][k] = bf16(x[b,f,s*90+k, n0+c]).
    // thread -> (c = tid%96, k-half = tid/96): lanes give contiguous c runs.
    {
        const int c  = tid % NT;
        const int kh = tid / NT;            // 0..1, k in [kh*48, kh*48+48)
        const float* xp = x + (((size_t)b * NF + f) * (NS * NK) + (size_t)s * NK) * NXYZ
                            + n0 + c;
        const int cs = (c & 7) << 4;
        #pragma unroll
        for (int kk = 0; kk < 48; kk += 8) {
            const int kb = kh * 48 + kk;
            float v[8];
            #pragma unroll
            for (int j = 0; j < 8; ++j) {
                const int k = kb + j;
                v[j] = (k < NK) ? xp[(size_t)k * NXYZ] : 0.f;
            }
            u32x4 u;
            u.x = pack2bf(v[0], v[1]);
            u.y = pack2bf(v[2], v[3]);
            u.z = pack2bf(v[4], v[5]);
            u.w = pack2bf(v[6], v[7]);
            *(u32x4*)(Bs + ((c * ROWB + kb * 2) ^ cs)) = u;
        }
    }

    const int lane = tid & 63;
    const int w  = tid / 64;       // wave 0..2 owns n-slice [w*32, w*32+32)
    const int lr = lane & 15;
    const int lg = lane >> 4;
    const int ls = (lr & 7) << 4;

    const size_t chan = (size_t)b * (NS * NF) + (size_t)s * NF + f;
    float* ybase = y + chan * ((size_t)NP * NXYZ);
    const int colbase = n0 + w * 32 + lr;

    // A-staging thread mapping (same every iteration)
    const int ar = tid & 63;       // p within tile
    const int akc = tid >> 6;      // 0..2 -> k-block of 32
    const int ars = (ar & 7) << 4;

    for (int pt = 0; pt < PTILES; ++pt) {
        const int p0 = pt * MT;

        __syncthreads();  // prev iteration's As reads done (also orders Bs stage)

        // ---- Stage A: As[r][k] = bf16(W[s][k][p0+r]), zero-padded.
        {
            const int p = p0 + ar;
            const bool pv = (p < NP);
            const float* wp = Wm + (size_t)s * NK * NP + p;
            #pragma unroll
            for (int kk = 0; kk < 32; kk += 8) {
                const int kb = akc * 32 + kk;
                float v[8];
                #pragma unroll
                for (int j = 0; j < 8; ++j) {
                    const int k = kb + j;
                    v[j] = (pv && (k < NK)) ? wp[(size_t)k * NP] : 0.f;
                }
                u32x4 u;
                u.x = pack2bf(v[0], v[1]);
                u.y = pack2bf(v[2], v[3]);
                u.z = pack2bf(v[4], v[5]);
                u.w = pack2bf(v[6], v[7]);
                *(u32x4*)(As + ((ar * ROWB + kb * 2) ^ ars)) = u;
            }
        }

        __syncthreads();

        // ---- Compute: 4 m-frags x 2 n-frags x 3 k-steps = 24 MFMA / wave.
        f32x4 acc[4][2];
        #pragma unroll
        for (int mi = 0; mi < 4; ++mi)
            #pragma unroll
            for (int ni = 0; ni < 2; ++ni)
                acc[mi][ni] = (f32x4){0.f, 0.f, 0.f, 0.f};

        #pragma unroll
        for (int kk = 0; kk < 3; ++kk) {
            const int kbyte = kk * 64 + lg * 16;
            bf16x8 a[4], bb[2];
            #pragma unroll
            for (int mi = 0; mi < 4; ++mi) {
                const int row = mi * 16 + lr;
                a[mi] = *(const bf16x8*)(As + ((row * ROWB + kbyte) ^ ls));
            }
            #pragma unroll
            for (int ni = 0; ni < 2; ++ni) {
                const int row = w * 32 + ni * 16 + lr;
                bb[ni] = *(const bf16x8*)(Bs + ((row * ROWB + kbyte) ^ ls));
            }
            #pragma unroll
            for (int mi = 0; mi < 4; ++mi)
                #pragma unroll
                for (int ni = 0; ni < 2; ++ni)
                    acc[mi][ni] = __builtin_amdgcn_mfma_f32_16x16x32_bf16(
                        a[mi], bb[ni], acc[mi][ni], 0, 0, 0);
        }

        // ---- Store: row = p (m), col = xyz (n). 16-lane groups -> 64B segs.
        #pragma unroll
        for (int mi = 0; mi < 4; ++mi) {
            const int prow = p0 + mi * 16 + lg * 4;
            #pragma unroll
            for (int r = 0; r < 4; ++r) {
                const int p = prow + r;
                if (p < NP) {
                    float* dst = ybase + (size_t)p * NXYZ + colbase;
                    #pragma unroll
                    for (int ni = 0; ni < 2; ++ni)
                        dst[ni * 16] = acc[mi][ni][r];
                }
            }
        }
    }
}

extern "C" void kernel_launch(void* const* d_in, const int* in_sizes, int n_in,
                              void* d_out, int out_size, void* d_ws, size_t ws_size,
                              hipStream_t stream) {
    (void)in_sizes; (void)n_in; (void)d_ws; (void)ws_size; (void)out_size;
    const float* x  = (const float*)d_in[0];
    const float* Wm = (const float*)d_in[1];
    // d_in[2] (shell_inverse) is sorted contiguous by construction -> static layout.
    float* y = (float*)d_out;
    dim3 grid(NB * NS * NF * NTILES);  // 1152
    interp_mfma<<<grid, 192, 0, stream>>>(x, Wm, y);
}

// Round 3
// 93.225 us; speedup vs baseline: 1.2087x; 1.2087x over previous
//
#include <hip/hip_runtime.h>
#include <cstdint>
#include <cstddef>

// Problem constants
#define NB 2
#define NF 8
#define NS 4
#define NK 90      // real K (dirs per shell)
#define NP 642     // grid vertices
#define NXYZ 1728  // 12*12*12
#define KP 96      // K padded to multiple of 32
#define MT 64      // p-tile (per inner iteration)
#define NT 96      // xyz-tile (1728 = 18*96 exact)
#define PTILES 11  // ceil(642/64)  — looped INSIDE the block
#define NTILES 18
#define ROWB (KP * 2)  // LDS row stride in bytes (96 bf16)

typedef __attribute__((ext_vector_type(8))) __bf16 bf16x8;
typedef __attribute__((ext_vector_type(4))) float f32x4;
typedef __attribute__((ext_vector_type(4))) uint32_t u32x4;

// RNE pack of two f32 -> u32 holding 2 bf16
__device__ __forceinline__ uint32_t pack2bf(float a, float b) {
    uint32_t ua = __builtin_bit_cast(uint32_t, a);
    uint32_t ub = __builtin_bit_cast(uint32_t, b);
    ua += 0x7FFFu + ((ua >> 16) & 1u);
    ub += 0x7FFFu + ((ub >> 16) & 1u);
    return (ua >> 16) | (ub & 0xFFFF0000u);
}

__global__ __launch_bounds__(192, 4) void interp_mfma(
    const float* __restrict__ x, const float* __restrict__ Wm,
    float* __restrict__ y)
{
    // XOR-swizzled LDS tiles: byte-offset ^= ((row&7)<<4). Same formula on
    // write and read sides (validated rounds 1-2: absmax = bf16 rounding).
    __shared__ __align__(16) char As[MT * ROWB];  // 12 KB  W[s]^T rows [p][k]
    __shared__ __align__(16) char Bs[NT * ROWB];  // 18 KB  x^T rows   [xyz][k]

    int blk = (int)blockIdx.x;
    const int nt = blk % NTILES; blk /= NTILES;
    const int f  = blk % NF;     blk /= NF;
    const int s  = blk % NS;     blk /= NS;
    const int b  = blk;

    const int tid = (int)threadIdx.x;
    const int n0 = nt * NT;

    // ---- Stage B ONCE: Bs[c][k] = bf16(x[b,f,s*90+k, n0+c]).
    {
        const int c  = tid % NT;
        const int kh = tid / NT;            // 0..1, k in [kh*48, kh*48+48)
        const float* xp = x + (((size_t)b * NF + f) * (NS * NK) + (size_t)s * NK) * NXYZ
                            + n0 + c;
        const int cs = (c & 7) << 4;
        #pragma unroll
        for (int kk = 0; kk < 48; kk += 8) {
            const int kb = kh * 48 + kk;
            float v[8];
            #pragma unroll
            for (int j = 0; j < 8; ++j) {
                const int k = kb + j;
                v[j] = (k < NK) ? xp[(size_t)k * NXYZ] : 0.f;
            }
            u32x4 u;
            u.x = pack2bf(v[0], v[1]);
            u.y = pack2bf(v[2], v[3]);
            u.z = pack2bf(v[4], v[5]);
            u.w = pack2bf(v[6], v[7]);
            *(u32x4*)(Bs + ((c * ROWB + kb * 2) ^ cs)) = u;
        }
    }

    const int lane = tid & 63;
    const int w  = tid / 64;       // wave w owns xyz-slice [w*32, w*32+32)
    const int lr = lane & 15;
    const int lg = lane >> 4;
    const int ls = (lr & 7) << 4;

    const size_t chan = (size_t)b * (NS * NF) + (size_t)s * NF + f;
    float* ybase = y + chan * ((size_t)NP * NXYZ);
    const int xyzbase = n0 + w * 32 + lg * 4;  // thread's first xyz col

    // A-staging thread mapping (same every iteration)
    const int ar = tid & 63;       // p within tile
    const int akc = tid >> 6;      // 0..2 -> k-block of 32
    const int ars = (ar & 7) << 4;

    for (int pt = 0; pt < PTILES; ++pt) {
        const int p0 = pt * MT;

        __syncthreads();  // prev iteration's As reads done (also orders Bs stage)

        // ---- Stage A: As[r][k] = bf16(W[s][k][p0+r]), zero-padded.
        {
            const int p = p0 + ar;
            const bool pv = (p < NP);
            const float* wp = Wm + (size_t)s * NK * NP + p;
            #pragma unroll
            for (int kk = 0; kk < 32; kk += 8) {
                const int kb = akc * 32 + kk;
                float v[8];
                #pragma unroll
                for (int j = 0; j < 8; ++j) {
                    const int k = kb + j;
                    v[j] = (pv && (k < NK)) ? wp[(size_t)k * NP] : 0.f;
                }
                u32x4 u;
                u.x = pack2bf(v[0], v[1]);
                u.y = pack2bf(v[2], v[3]);
                u.z = pack2bf(v[4], v[5]);
                u.w = pack2bf(v[6], v[7]);
                *(u32x4*)(As + ((ar * ROWB + kb * 2) ^ ars)) = u;
            }
        }

        __syncthreads();

        // ---- Compute (SWAPPED operands): acc row = xyz, col = p.
        // Wave w: 2 xyz-frags x 4 p-frags x 3 k-steps = 24 MFMA.
        f32x4 acc[2][4];
        #pragma unroll
        for (int mi = 0; mi < 2; ++mi)
            #pragma unroll
            for (int ni = 0; ni < 4; ++ni)
                acc[mi][ni] = (f32x4){0.f, 0.f, 0.f, 0.f};

        #pragma unroll
        for (int kk = 0; kk < 3; ++kk) {
            const int kbyte = kk * 64 + lg * 16;
            bf16x8 bxyz[2], ap[4];
            #pragma unroll
            for (int mi = 0; mi < 2; ++mi) {
                const int row = w * 32 + mi * 16 + lr;
                bxyz[mi] = *(const bf16x8*)(Bs + ((row * ROWB + kbyte) ^ ls));
            }
            #pragma unroll
            for (int ni = 0; ni < 4; ++ni) {
                const int row = ni * 16 + lr;
                ap[ni] = *(const bf16x8*)(As + ((row * ROWB + kbyte) ^ ls));
            }
            #pragma unroll
            for (int mi = 0; mi < 2; ++mi)
                #pragma unroll
                for (int ni = 0; ni < 4; ++ni)
                    acc[mi][ni] = __builtin_amdgcn_mfma_f32_16x16x32_bf16(
                        bxyz[mi], ap[ni], acc[mi][ni], 0, 0, 0);
        }

        // ---- Store: row = p (col of acc), thread holds 4 consecutive xyz
        // (acc regs r = rows lg*4+r) -> float4 nontemporal stores, 1KB/instr.
        #pragma unroll
        for (int ni = 0; ni < 4; ++ni) {
            const int p = p0 + ni * 16 + lr;
            if (p < NP) {
                float* dst = ybase + (size_t)p * NXYZ + xyzbase;
                __builtin_nontemporal_store(acc[0][ni], (f32x4*)dst);
                __builtin_nontemporal_store(acc[1][ni], (f32x4*)(dst + 16));
            }
        }
    }
}

extern "C" void kernel_launch(void* const* d_in, const int* in_sizes, int n_in,
                              void* d_out, int out_size, void* d_ws, size_t ws_size,
                              hipStream_t stream) {
    (void)in_sizes; (void)n_in; (void)d_ws; (void)ws_size; (void)out_size;
    const float* x  = (const float*)d_in[0];
    const float* Wm = (const float*)d_in[1];
    // d_in[2] (shell_inverse) is sorted contiguous by construction -> static layout.
    float* y = (float*)d_out;
    dim3 grid(NB * NS * NF * NTILES);  // 1152
    interp_mfma<<<grid, 192, 0, stream>>>(x, Wm, y);
}